// Round 9
// baseline (710.453 us; speedup 1.0000x reference)
//
#include <hip/hip_runtime.h>
#include <math.h>

#define B 8
#define C 512
#define L 8192
#define N 512      // L/CS chunk steps
#define C8 64      // C/8 bottleneck dim
#define CTILE 8    // channels per P1 job
#define JPB 224    // jobs per batch: 64 P1 + 32 P2 + 128 A
#define TOTAL_JOBS (B * JPB)   // 1792
#define GRID 768   // 3 blocks/CU * 256 CUs -> all co-resident

// ---------------------------------------------------------------------------
// Single mega-kernel: per-batch pipeline {pool+EMA -> SE -> apply} scheduled
// over 768 co-resident blocks via device-scope flags. apply(b) runs ~2 batches
// after pool(b) read x_b, so x_b is still L3-resident when re-read.
// ---------------------------------------------------------------------------
__device__ __forceinline__ void spin_wait(int* p, int target) {
    if (threadIdx.x == 0) {
        while (__hip_atomic_load(p, __ATOMIC_ACQUIRE, __HIP_MEMORY_SCOPE_AGENT) < target)
            __builtin_amdgcn_s_sleep(16);
    }
    __syncthreads();
}

__device__ __forceinline__ void publish(int* p) {
    // callers arrive here right after __syncthreads() (all stores drained);
    // release RMW orders all prior global stores before the increment.
    if (threadIdx.x == 0) {
        __hip_atomic_fetch_add(p, 1, __ATOMIC_RELEASE, __HIP_MEMORY_SCOPE_AGENT);
    }
}

__global__ __launch_bounds__(256, 3) void mega_k(
    const float* __restrict__ x, const float* __restrict__ gamma,
    const float* __restrict__ w1, const float* __restrict__ b1,
    const float* __restrict__ w2, const float* __restrict__ b2,
    float* __restrict__ out, float* e, float* gate, int* cnt) {

    __shared__ __align__(16) char smem[36864];   // union of phase layouts
    const int t = threadIdx.x;

    for (int gj = blockIdx.x; gj < TOTAL_JOBS; gj += GRID) {
        const int b = gj / JPB;
        const int r = gj - b * JPB;

        if (r < 64) {
            // ================= P1: pool + full EMA, channels r*8..+7 =======
            // cm stride 545: addr = cl*545 + seg*17 + step (conflict-free scan)
            float* cm      = (float*)smem;                    // 8*545 floats
            float* carry_s = (float*)(smem + 17440);          // [8][32]
            float* pre_s   = (float*)(smem + 18464);          // [8][32]
            const int ct = r;
            const int w = t >> 6, lane = t & 63;
#pragma unroll
            for (int cr = 0; cr < 2; ++cr) {
                const int cl = w + 4 * cr;
                const size_t row4 = (size_t)(b * C + ct * CTILE + cl) * (L / 4);
#pragma unroll
                for (int rr = 0; rr < 4; ++rr) {
                    float4 f[8];
#pragma unroll
                    for (int u = 0; u < 8; ++u)
                        f[u] = reinterpret_cast<const float4*>(x)[row4 + rr * 512 + u * 64 + lane];
#pragma unroll
                    for (int u = 0; u < 8; ++u) {
                        float s = f[u].x + f[u].y + f[u].z + f[u].w;
                        s += __shfl_down(s, 1, 4);
                        s += __shfl_down(s, 2, 4);
                        if ((lane & 3) == 0) {
                            const int chunk = rr * 128 + u * 16 + (lane >> 2);
                            cm[cl * 545 + (chunk >> 4) * 17 + (chunk & 15)] = s * (1.0f / 16.0f);
                        }
                    }
                }
            }
            __syncthreads();
            // EMA: thread = (cl = t>>5, seg = t&31), 16 steps each
            const int cl = t >> 5, s = t & 31;
            const float g = gamma[ct * CTILE + cl];
            const float omg = 1.0f - g;
            {
                float y = 0.0f;
#pragma unroll
                for (int i = 0; i < 16; ++i)
                    y = fmaf(g, y, omg * cm[cl * 545 + s * 17 + i]);
                carry_s[cl * 32 + s] = y;
            }
            __syncthreads();
            if (t < CTILE) {
                const float gg = gamma[ct * CTILE + t];
                float g16 = gg * gg; g16 *= g16; g16 *= g16; g16 *= g16;   // g^16
                float E = 0.0f;
#pragma unroll
                for (int ss = 0; ss < 32; ++ss) {
                    pre_s[t * 32 + ss] = E;
                    E = fmaf(g16, E, carry_s[t * 32 + ss]);
                }
            }
            __syncthreads();
            {
                float y = pre_s[cl * 32 + s];
#pragma unroll
                for (int i = 0; i < 16; ++i) {
                    y = fmaf(g, y, omg * cm[cl * 545 + s * 17 + i]);
                    cm[cl * 545 + s * 17 + i] = y;
                }
            }
            __syncthreads();
            // write e [B,N,C]
            float* ebase = e + (size_t)b * N * C + ct * CTILE;
#pragma unroll
            for (int rr = 0; rr < 16; ++rr) {
                const int idx = rr * 256 + t;
                const int n = idx >> 3, c2 = idx & 7;
                ebase[(size_t)n * C + c2] = cm[c2 * 545 + (n >> 4) * 17 + (n & 15)];
            }
            __syncthreads();
            publish(&cnt[b]);

        } else if (r < 96) {
            // ================= P2: SE for rows n0..n0+15 of batch b =========
            spin_wait(&cnt[b], 64);
            float* es = (float*)smem;             // [16][512]
            float* hs = (float*)(smem + 32768);   // [16][64]
            const int sub = r - 64;
            const size_t row0 = (size_t)b * N + sub * 16;

            const float4* esrc = reinterpret_cast<const float4*>(e + row0 * C);
            float4* esw = reinterpret_cast<float4*>(es);
#pragma unroll
            for (int i = 0; i < 8; ++i)
                esw[i * 256 + t] = esrc[i * 256 + t];
            __syncthreads();

            // GEMM1: h[16][64] = relu(e x w1^T + b1)
            {
                const int o = t & 63, jr = t >> 6;
                float acc[4] = {0.f, 0.f, 0.f, 0.f};
                const float4* wrow = reinterpret_cast<const float4*>(w1 + (size_t)o * C);
                const float4* es4 = reinterpret_cast<const float4*>(es);
#pragma unroll 4
                for (int k4 = 0; k4 < 128; ++k4) {
                    const float4 wv = wrow[k4];
#pragma unroll
                    for (int i = 0; i < 4; ++i) {
                        const float4 ev = es4[(jr + i * 4) * 128 + k4];
                        acc[i] = fmaf(wv.x, ev.x, acc[i]); acc[i] = fmaf(wv.y, ev.y, acc[i]);
                        acc[i] = fmaf(wv.z, ev.z, acc[i]); acc[i] = fmaf(wv.w, ev.w, acc[i]);
                    }
                }
                const float bb = b1[o];
#pragma unroll
                for (int i = 0; i < 4; ++i)
                    hs[(jr + i * 4) * 64 + o] = fmaxf(acc[i] + bb, 0.f);
            }
            __syncthreads();

            // GEMM2: gate[16 n][512 c], thread owns c0=t, c1=t+256
            {
                float acc0[16], acc1[16];
                const float bb0 = b2[t], bb1 = b2[t + 256];
#pragma unroll
                for (int j = 0; j < 16; ++j) { acc0[j] = bb0; acc1[j] = bb1; }
                const float4* w20 = reinterpret_cast<const float4*>(w2 + (size_t)t * C8);
                const float4* w21 = reinterpret_cast<const float4*>(w2 + (size_t)(t + 256) * C8);
                const float4* hs4 = reinterpret_cast<const float4*>(hs);
#pragma unroll
                for (int k4 = 0; k4 < 16; ++k4) {
                    const float4 wa = w20[k4];
                    const float4 wb = w21[k4];
#pragma unroll
                    for (int j = 0; j < 16; ++j) {
                        const float4 hv = hs4[j * 16 + k4];
                        acc0[j] = fmaf(wa.x, hv.x, acc0[j]); acc0[j] = fmaf(wa.y, hv.y, acc0[j]);
                        acc0[j] = fmaf(wa.z, hv.z, acc0[j]); acc0[j] = fmaf(wa.w, hv.w, acc0[j]);
                        acc1[j] = fmaf(wb.x, hv.x, acc1[j]); acc1[j] = fmaf(wb.y, hv.y, acc1[j]);
                        acc1[j] = fmaf(wb.z, hv.z, acc1[j]); acc1[j] = fmaf(wb.w, hv.w, acc1[j]);
                    }
                }
                float* g0 = gate + ((size_t)(b * C + t)) * N + sub * 16;
                float* g1 = gate + ((size_t)(b * C + t + 256)) * N + sub * 16;
#pragma unroll
                for (int q = 0; q < 4; ++q) {
                    float4 o4;
                    o4.x = 1.0f / (1.0f + __expf(-acc0[q * 4 + 0]));
                    o4.y = 1.0f / (1.0f + __expf(-acc0[q * 4 + 1]));
                    o4.z = 1.0f / (1.0f + __expf(-acc0[q * 4 + 2]));
                    o4.w = 1.0f / (1.0f + __expf(-acc0[q * 4 + 3]));
                    reinterpret_cast<float4*>(g0)[q] = o4;
                }
#pragma unroll
                for (int q = 0; q < 4; ++q) {
                    float4 o4;
                    o4.x = 1.0f / (1.0f + __expf(-acc1[q * 4 + 0]));
                    o4.y = 1.0f / (1.0f + __expf(-acc1[q * 4 + 1]));
                    o4.z = 1.0f / (1.0f + __expf(-acc1[q * 4 + 2]));
                    o4.w = 1.0f / (1.0f + __expf(-acc1[q * 4 + 3]));
                    reinterpret_cast<float4*>(g1)[q] = o4;
                }
            }
            __syncthreads();
            publish(&cnt[8 + b]);

        } else {
            // ================= A: apply gate to 1/128 of batch b ============
            spin_wait(&cnt[8 + b], 32);
            const int sub = r - 96;
            const size_t base4 = ((size_t)b << 20) + ((size_t)sub << 13);
#pragma unroll 8
            for (int i = 0; i < 32; ++i) {
                const size_t idx = base4 + i * 256 + t;
                const int bc = (int)(idx >> 11);
                const int n = ((int)idx & 2047) >> 2;
                const float g = gate[(size_t)bc * N + n];
                float4 v = reinterpret_cast<const float4*>(x)[idx];
                v.x *= g; v.y *= g; v.z *= g; v.w *= g;
                reinterpret_cast<float4*>(out)[idx] = v;
            }
        }
    }
}

// ---------------------------------------------------------------------------
extern "C" void kernel_launch(void* const* d_in, const int* in_sizes, int n_in,
                              void* d_out, int out_size, void* d_ws, size_t ws_size,
                              hipStream_t stream) {
    const float* x     = (const float*)d_in[0];
    const float* gamma = (const float*)d_in[1];
    const float* w1    = (const float*)d_in[2];
    const float* b1    = (const float*)d_in[3];
    const float* w2    = (const float*)d_in[4];
    const float* b2    = (const float*)d_in[5];
    float* out = (float*)d_out;

    char* ws = (char*)d_ws;
    int*   cnt  = (int*)ws;                          // 16 flags (64 B)
    float* e    = (float*)(ws + 256);                // 8 MB [B,N,C]
    float* gate = (float*)(ws + 256 + (size_t)B * N * C * 4);   // 8 MB [B,C,N]

    // zero the pipeline flags (graph-capturable async memset)
    (void)hipMemsetAsync(cnt, 0, 64, stream);
    mega_k<<<GRID, 256, 0, stream>>>(x, gamma, w1, b1, w2, b2, out, e, gate, cnt);
}

// Round 10
// 423.610 us; speedup vs baseline: 1.6771x; 1.6771x over previous
//
#include <hip/hip_runtime.h>
#include <math.h>

#define B 8
#define C 512
#define L 8192
#define N 512      // L/CS chunk steps
#define C8 64      // C/8 bottleneck dim
#define CTILE 8    // channels per P1 job
#define GRID 768   // 3 blocks/CU x 256 CUs -> all co-resident (validated R9)

// ---------------------------------------------------------------------------
// Grid-wide barrier: monotonic counter, one arrive per block per barrier.
// All GRID blocks are co-resident (36 KB LDS, VGPR<=168 via launch_bounds),
// so spinning is deadlock-free. Release RMW publishes prior stores;
// acquire load invalidates caches for cross-XCD visibility (validated R9).
// ---------------------------------------------------------------------------
__device__ __forceinline__ void gbarrier(int* ctr, int target) {
    __syncthreads();
    if (threadIdx.x == 0) {
        __hip_atomic_fetch_add(ctr, 1, __ATOMIC_RELEASE, __HIP_MEMORY_SCOPE_AGENT);
        while (__hip_atomic_load(ctr, __ATOMIC_ACQUIRE, __HIP_MEMORY_SCOPE_AGENT) < target)
            __builtin_amdgcn_s_sleep(2);
    }
    __syncthreads();
}

__global__ __launch_bounds__(256, 3) void mega_k(
    const float* __restrict__ x, const float* __restrict__ gamma,
    const float* __restrict__ w1, const float* __restrict__ b1,
    const float* __restrict__ w2, const float* __restrict__ b2,
    float* __restrict__ out, float* e, float* gate, int* cnt) {

    __shared__ __align__(16) char smem[36864];   // P1: 19.5 KB, P2: 36 KB
    const int t = threadIdx.x;
    const int bid = blockIdx.x;

    // ================= Phase 1: pool + full EMA (512 jobs) ==================
    if (bid < 512) {
        const int b = bid >> 6;
        const int ct = bid & 63;
        // cm stride 545: addr = cl*545 + seg*17 + step (conflict-free scan)
        float* cm      = (float*)smem;                    // 8*545 floats
        float* carry_s = (float*)(smem + 17440);          // [8][32]
        float* pre_s   = (float*)(smem + 18464);          // [8][32]
        const int w = t >> 6, lane = t & 63;
#pragma unroll
        for (int cr = 0; cr < 2; ++cr) {
            const int cl = w + 4 * cr;
            const size_t row4 = (size_t)(b * C + ct * CTILE + cl) * (L / 4);
#pragma unroll
            for (int rr = 0; rr < 4; ++rr) {
                float4 f[8];
#pragma unroll
                for (int u = 0; u < 8; ++u)
                    f[u] = reinterpret_cast<const float4*>(x)[row4 + rr * 512 + u * 64 + lane];
#pragma unroll
                for (int u = 0; u < 8; ++u) {
                    float s = f[u].x + f[u].y + f[u].z + f[u].w;
                    s += __shfl_down(s, 1, 4);
                    s += __shfl_down(s, 2, 4);
                    if ((lane & 3) == 0) {
                        const int chunk = rr * 128 + u * 16 + (lane >> 2);
                        cm[cl * 545 + (chunk >> 4) * 17 + (chunk & 15)] = s * (1.0f / 16.0f);
                    }
                }
            }
        }
        __syncthreads();
        // EMA: thread = (cl = t>>5, seg = t&31), 16 steps each
        const int cl = t >> 5, s = t & 31;
        const float g = gamma[ct * CTILE + cl];
        const float omg = 1.0f - g;
        {
            float y = 0.0f;
#pragma unroll
            for (int i = 0; i < 16; ++i)
                y = fmaf(g, y, omg * cm[cl * 545 + s * 17 + i]);
            carry_s[cl * 32 + s] = y;
        }
        __syncthreads();
        if (t < CTILE) {
            const float gg = gamma[ct * CTILE + t];
            float g16 = gg * gg; g16 *= g16; g16 *= g16; g16 *= g16;   // g^16
            float E = 0.0f;
#pragma unroll
            for (int ss = 0; ss < 32; ++ss) {
                pre_s[t * 32 + ss] = E;
                E = fmaf(g16, E, carry_s[t * 32 + ss]);
            }
        }
        __syncthreads();
        {
            float y = pre_s[cl * 32 + s];
#pragma unroll
            for (int i = 0; i < 16; ++i) {
                y = fmaf(g, y, omg * cm[cl * 545 + s * 17 + i]);
                cm[cl * 545 + s * 17 + i] = y;
            }
        }
        __syncthreads();
        // write e [B,N,C]
        float* ebase = e + (size_t)b * N * C + ct * CTILE;
#pragma unroll
        for (int rr = 0; rr < 16; ++rr) {
            const int idx = rr * 256 + t;
            const int n = idx >> 3, c2 = idx & 7;
            ebase[(size_t)n * C + c2] = cm[c2 * 545 + (n >> 4) * 17 + (n & 15)];
        }
    }
    gbarrier(&cnt[0], GRID);

    // ================= Phase 2: SE bottleneck (256 jobs) ====================
    if (bid < 256) {
        const int b = bid >> 5;
        const int sub = bid & 31;
        float* es = (float*)smem;             // [16][512]
        float* hs = (float*)(smem + 32768);   // [16][64]
        const size_t row0 = (size_t)b * N + sub * 16;

        const float4* esrc = reinterpret_cast<const float4*>(e + row0 * C);
        float4* esw = reinterpret_cast<float4*>(es);
#pragma unroll
        for (int i = 0; i < 8; ++i)
            esw[i * 256 + t] = esrc[i * 256 + t];
        __syncthreads();

        // GEMM1: h[16][64] = relu(e x w1^T + b1)
        {
            const int o = t & 63, jr = t >> 6;
            float acc[4] = {0.f, 0.f, 0.f, 0.f};
            const float4* wrow = reinterpret_cast<const float4*>(w1 + (size_t)o * C);
            const float4* es4 = reinterpret_cast<const float4*>(es);
#pragma unroll 4
            for (int k4 = 0; k4 < 128; ++k4) {
                const float4 wv = wrow[k4];
#pragma unroll
                for (int i = 0; i < 4; ++i) {
                    const float4 ev = es4[(jr + i * 4) * 128 + k4];
                    acc[i] = fmaf(wv.x, ev.x, acc[i]); acc[i] = fmaf(wv.y, ev.y, acc[i]);
                    acc[i] = fmaf(wv.z, ev.z, acc[i]); acc[i] = fmaf(wv.w, ev.w, acc[i]);
                }
            }
            const float bb = b1[o];
#pragma unroll
            for (int i = 0; i < 4; ++i)
                hs[(jr + i * 4) * 64 + o] = fmaxf(acc[i] + bb, 0.f);
        }
        __syncthreads();

        // GEMM2: gate[16 n][512 c] -> gate buffer [B,C,N]; thread owns c, c+256
        {
            float acc0[16], acc1[16];
            const float bb0 = b2[t], bb1 = b2[t + 256];
#pragma unroll
            for (int j = 0; j < 16; ++j) { acc0[j] = bb0; acc1[j] = bb1; }
            const float4* w20 = reinterpret_cast<const float4*>(w2 + (size_t)t * C8);
            const float4* w21 = reinterpret_cast<const float4*>(w2 + (size_t)(t + 256) * C8);
            const float4* hs4 = reinterpret_cast<const float4*>(hs);
#pragma unroll
            for (int k4 = 0; k4 < 16; ++k4) {
                const float4 wa = w20[k4];
                const float4 wb = w21[k4];
#pragma unroll
                for (int j = 0; j < 16; ++j) {
                    const float4 hv = hs4[j * 16 + k4];
                    acc0[j] = fmaf(wa.x, hv.x, acc0[j]); acc0[j] = fmaf(wa.y, hv.y, acc0[j]);
                    acc0[j] = fmaf(wa.z, hv.z, acc0[j]); acc0[j] = fmaf(wa.w, hv.w, acc0[j]);
                    acc1[j] = fmaf(wb.x, hv.x, acc1[j]); acc1[j] = fmaf(wb.y, hv.y, acc1[j]);
                    acc1[j] = fmaf(wb.z, hv.z, acc1[j]); acc1[j] = fmaf(wb.w, hv.w, acc1[j]);
                }
            }
            float* g0 = gate + ((size_t)(b * C + t)) * N + sub * 16;
            float* g1 = gate + ((size_t)(b * C + t + 256)) * N + sub * 16;
#pragma unroll
            for (int q = 0; q < 4; ++q) {
                float4 o4;
                o4.x = 1.0f / (1.0f + __expf(-acc0[q * 4 + 0]));
                o4.y = 1.0f / (1.0f + __expf(-acc0[q * 4 + 1]));
                o4.z = 1.0f / (1.0f + __expf(-acc0[q * 4 + 2]));
                o4.w = 1.0f / (1.0f + __expf(-acc0[q * 4 + 3]));
                reinterpret_cast<float4*>(g0)[q] = o4;
            }
#pragma unroll
            for (int q = 0; q < 4; ++q) {
                float4 o4;
                o4.x = 1.0f / (1.0f + __expf(-acc1[q * 4 + 0]));
                o4.y = 1.0f / (1.0f + __expf(-acc1[q * 4 + 1]));
                o4.z = 1.0f / (1.0f + __expf(-acc1[q * 4 + 2]));
                o4.w = 1.0f / (1.0f + __expf(-acc1[q * 4 + 3]));
                reinterpret_cast<float4*>(g1)[q] = o4;
            }
        }
    }
    gbarrier(&cnt[1], GRID);

    // ================= Phase 3: apply gate (all blocks, grid-stride) ========
    {
        const int total4 = B * C * L / 4;          // 8,388,608 float4
#pragma unroll 4
        for (int idx = bid * 256 + t; idx < total4; idx += GRID * 256) {
            const int bc = idx >> 11;              // 2048 float4 per (b,c) row
            const int n = (idx & 2047) >> 2;
            const float g = gate[(size_t)bc * N + n];
            float4 v = reinterpret_cast<const float4*>(x)[idx];
            v.x *= g; v.y *= g; v.z *= g; v.w *= g;
            reinterpret_cast<float4*>(out)[idx] = v;
        }
    }
}

// ---------------------------------------------------------------------------
extern "C" void kernel_launch(void* const* d_in, const int* in_sizes, int n_in,
                              void* d_out, int out_size, void* d_ws, size_t ws_size,
                              hipStream_t stream) {
    const float* x     = (const float*)d_in[0];
    const float* gamma = (const float*)d_in[1];
    const float* w1    = (const float*)d_in[2];
    const float* b1    = (const float*)d_in[3];
    const float* w2    = (const float*)d_in[4];
    const float* b2    = (const float*)d_in[5];
    float* out = (float*)d_out;

    char* ws = (char*)d_ws;
    int*   cnt  = (int*)ws;                          // 2 barrier counters
    float* e    = (float*)(ws + 256);                // 8 MB [B,N,C]
    float* gate = (float*)(ws + 256 + (size_t)B * N * C * 4);   // 8 MB [B,C,N]

    (void)hipMemsetAsync(cnt, 0, 64, stream);
    mega_k<<<GRID, 256, 0, stream>>>(x, gamma, w1, b1, w2, b2, out, e, gate, cnt);
}

// Round 11
// 240.078 us; speedup vs baseline: 2.9593x; 1.7645x over previous
//
#include <hip/hip_runtime.h>
#include <math.h>

#define B 8
#define C 512
#define L 8192
#define N 512      // L/CS chunk steps
#define C8 64      // C/8 bottleneck dim
#define CTILE 8    // channels per P1 job
#define GRID 768   // 3 blocks/CU x 256 CUs -> all co-resident (validated R9/R10)

// ---------------------------------------------------------------------------
// Grid-wide barrier. KEY FIX vs R10: poll with RELAXED loads (no cache
// invalidate per iteration), single ACQUIRE load after exit. R10's
// acquire-per-poll invalidated every XCD's L2 ~3x/us for the whole phase,
// forcing all working loads to L3/HBM latency (620 GB/s, VALU 3%).
// Ordering stays correct: producers' release-RMWs complete before the
// counter reaches target; one acquire invalidate then precedes any read.
// ---------------------------------------------------------------------------
__device__ __forceinline__ void gbarrier(int* ctr, int target) {
    __syncthreads();
    if (threadIdx.x == 0) {
        __hip_atomic_fetch_add(ctr, 1, __ATOMIC_RELEASE, __HIP_MEMORY_SCOPE_AGENT);
        while (__hip_atomic_load(ctr, __ATOMIC_RELAXED, __HIP_MEMORY_SCOPE_AGENT) < target)
            __builtin_amdgcn_s_sleep(32);
        (void)__hip_atomic_load(ctr, __ATOMIC_ACQUIRE, __HIP_MEMORY_SCOPE_AGENT);
    }
    __syncthreads();
}

__global__ __launch_bounds__(256, 3) void mega_k(
    const float* __restrict__ x, const float* __restrict__ gamma,
    const float* __restrict__ w1, const float* __restrict__ b1,
    const float* __restrict__ w2, const float* __restrict__ b2,
    float* __restrict__ out, float* e, float* gate, int* cnt) {

    __shared__ __align__(16) char smem[36864];   // P1: 19.5 KB, P2: 36 KB
    const int t = threadIdx.x;
    const int bid = blockIdx.x;

    // ================= Phase 1: pool + full EMA (512 jobs) ==================
    if (bid < 512) {
        const int b = bid >> 6;
        const int ct = bid & 63;
        // cm stride 545: addr = cl*545 + seg*17 + step (conflict-free scan)
        float* cm      = (float*)smem;                    // 8*545 floats
        float* carry_s = (float*)(smem + 17440);          // [8][32]
        float* pre_s   = (float*)(smem + 18464);          // [8][32]
        const int w = t >> 6, lane = t & 63;
#pragma unroll
        for (int cr = 0; cr < 2; ++cr) {
            const int cl = w + 4 * cr;
            const size_t row4 = (size_t)(b * C + ct * CTILE + cl) * (L / 4);
#pragma unroll
            for (int rr = 0; rr < 4; ++rr) {
                float4 f[8];
#pragma unroll
                for (int u = 0; u < 8; ++u)
                    f[u] = reinterpret_cast<const float4*>(x)[row4 + rr * 512 + u * 64 + lane];
#pragma unroll
                for (int u = 0; u < 8; ++u) {
                    float s = f[u].x + f[u].y + f[u].z + f[u].w;
                    s += __shfl_down(s, 1, 4);
                    s += __shfl_down(s, 2, 4);
                    if ((lane & 3) == 0) {
                        const int chunk = rr * 128 + u * 16 + (lane >> 2);
                        cm[cl * 545 + (chunk >> 4) * 17 + (chunk & 15)] = s * (1.0f / 16.0f);
                    }
                }
            }
        }
        __syncthreads();
        // EMA: thread = (cl = t>>5, seg = t&31), 16 steps each
        const int cl = t >> 5, s = t & 31;
        const float g = gamma[ct * CTILE + cl];
        const float omg = 1.0f - g;
        {
            float y = 0.0f;
#pragma unroll
            for (int i = 0; i < 16; ++i)
                y = fmaf(g, y, omg * cm[cl * 545 + s * 17 + i]);
            carry_s[cl * 32 + s] = y;
        }
        __syncthreads();
        if (t < CTILE) {
            const float gg = gamma[ct * CTILE + t];
            float g16 = gg * gg; g16 *= g16; g16 *= g16; g16 *= g16;   // g^16
            float E = 0.0f;
#pragma unroll
            for (int ss = 0; ss < 32; ++ss) {
                pre_s[t * 32 + ss] = E;
                E = fmaf(g16, E, carry_s[t * 32 + ss]);
            }
        }
        __syncthreads();
        {
            float y = pre_s[cl * 32 + s];
#pragma unroll
            for (int i = 0; i < 16; ++i) {
                y = fmaf(g, y, omg * cm[cl * 545 + s * 17 + i]);
                cm[cl * 545 + s * 17 + i] = y;
            }
        }
        __syncthreads();
        // write e [B,N,C]
        float* ebase = e + (size_t)b * N * C + ct * CTILE;
#pragma unroll
        for (int rr = 0; rr < 16; ++rr) {
            const int idx = rr * 256 + t;
            const int n = idx >> 3, c2 = idx & 7;
            ebase[(size_t)n * C + c2] = cm[c2 * 545 + (n >> 4) * 17 + (n & 15)];
        }
    }
    gbarrier(&cnt[0], GRID);

    // ================= Phase 2: SE bottleneck (256 jobs) ====================
    if (bid < 256) {
        const int b = bid >> 5;
        const int sub = bid & 31;
        float* es = (float*)smem;             // [16][512]
        float* hs = (float*)(smem + 32768);   // [16][64]
        const size_t row0 = (size_t)b * N + sub * 16;

        const float4* esrc = reinterpret_cast<const float4*>(e + row0 * C);
        float4* esw = reinterpret_cast<float4*>(es);
#pragma unroll
        for (int i = 0; i < 8; ++i)
            esw[i * 256 + t] = esrc[i * 256 + t];
        __syncthreads();

        // GEMM1: h[16][64] = relu(e x w1^T + b1)
        {
            const int o = t & 63, jr = t >> 6;
            float acc[4] = {0.f, 0.f, 0.f, 0.f};
            const float4* wrow = reinterpret_cast<const float4*>(w1 + (size_t)o * C);
            const float4* es4 = reinterpret_cast<const float4*>(es);
#pragma unroll 4
            for (int k4 = 0; k4 < 128; ++k4) {
                const float4 wv = wrow[k4];
#pragma unroll
                for (int i = 0; i < 4; ++i) {
                    const float4 ev = es4[(jr + i * 4) * 128 + k4];
                    acc[i] = fmaf(wv.x, ev.x, acc[i]); acc[i] = fmaf(wv.y, ev.y, acc[i]);
                    acc[i] = fmaf(wv.z, ev.z, acc[i]); acc[i] = fmaf(wv.w, ev.w, acc[i]);
                }
            }
            const float bb = b1[o];
#pragma unroll
            for (int i = 0; i < 4; ++i)
                hs[(jr + i * 4) * 64 + o] = fmaxf(acc[i] + bb, 0.f);
        }
        __syncthreads();

        // GEMM2: gate[16 n][512 c] -> gate buffer [B,C,N]; thread owns c, c+256
        {
            float acc0[16], acc1[16];
            const float bb0 = b2[t], bb1 = b2[t + 256];
#pragma unroll
            for (int j = 0; j < 16; ++j) { acc0[j] = bb0; acc1[j] = bb1; }
            const float4* w20 = reinterpret_cast<const float4*>(w2 + (size_t)t * C8);
            const float4* w21 = reinterpret_cast<const float4*>(w2 + (size_t)(t + 256) * C8);
            const float4* hs4 = reinterpret_cast<const float4*>(hs);
#pragma unroll
            for (int k4 = 0; k4 < 16; ++k4) {
                const float4 wa = w20[k4];
                const float4 wb = w21[k4];
#pragma unroll
                for (int j = 0; j < 16; ++j) {
                    const float4 hv = hs4[j * 16 + k4];
                    acc0[j] = fmaf(wa.x, hv.x, acc0[j]); acc0[j] = fmaf(wa.y, hv.y, acc0[j]);
                    acc0[j] = fmaf(wa.z, hv.z, acc0[j]); acc0[j] = fmaf(wa.w, hv.w, acc0[j]);
                    acc1[j] = fmaf(wb.x, hv.x, acc1[j]); acc1[j] = fmaf(wb.y, hv.y, acc1[j]);
                    acc1[j] = fmaf(wb.z, hv.z, acc1[j]); acc1[j] = fmaf(wb.w, hv.w, acc1[j]);
                }
            }
            float* g0 = gate + ((size_t)(b * C + t)) * N + sub * 16;
            float* g1 = gate + ((size_t)(b * C + t + 256)) * N + sub * 16;
#pragma unroll
            for (int q = 0; q < 4; ++q) {
                float4 o4;
                o4.x = 1.0f / (1.0f + __expf(-acc0[q * 4 + 0]));
                o4.y = 1.0f / (1.0f + __expf(-acc0[q * 4 + 1]));
                o4.z = 1.0f / (1.0f + __expf(-acc0[q * 4 + 2]));
                o4.w = 1.0f / (1.0f + __expf(-acc0[q * 4 + 3]));
                reinterpret_cast<float4*>(g0)[q] = o4;
            }
#pragma unroll
            for (int q = 0; q < 4; ++q) {
                float4 o4;
                o4.x = 1.0f / (1.0f + __expf(-acc1[q * 4 + 0]));
                o4.y = 1.0f / (1.0f + __expf(-acc1[q * 4 + 1]));
                o4.z = 1.0f / (1.0f + __expf(-acc1[q * 4 + 2]));
                o4.w = 1.0f / (1.0f + __expf(-acc1[q * 4 + 3]));
                reinterpret_cast<float4*>(g1)[q] = o4;
            }
        }
    }
    gbarrier(&cnt[1], GRID);

    // ================= Phase 3: apply gate (all blocks, grid-stride) ========
    {
        const int total4 = B * C * L / 4;          // 8,388,608 float4
#pragma unroll 4
        for (int idx = bid * 256 + t; idx < total4; idx += GRID * 256) {
            const int bc = idx >> 11;              // 2048 float4 per (b,c) row
            const int n = (idx & 2047) >> 2;
            const float g = gate[(size_t)bc * N + n];
            float4 v = reinterpret_cast<const float4*>(x)[idx];
            v.x *= g; v.y *= g; v.z *= g; v.w *= g;
            reinterpret_cast<float4*>(out)[idx] = v;
        }
    }
}

// ---------------------------------------------------------------------------
extern "C" void kernel_launch(void* const* d_in, const int* in_sizes, int n_in,
                              void* d_out, int out_size, void* d_ws, size_t ws_size,
                              hipStream_t stream) {
    const float* x     = (const float*)d_in[0];
    const float* gamma = (const float*)d_in[1];
    const float* w1    = (const float*)d_in[2];
    const float* b1    = (const float*)d_in[3];
    const float* w2    = (const float*)d_in[4];
    const float* b2    = (const float*)d_in[5];
    float* out = (float*)d_out;

    char* ws = (char*)d_ws;
    int*   cnt  = (int*)ws;                          // 2 barrier counters
    float* e    = (float*)(ws + 256);                // 8 MB [B,N,C]
    float* gate = (float*)(ws + 256 + (size_t)B * N * C * 4);   // 8 MB [B,C,N]

    (void)hipMemsetAsync(cnt, 0, 64, stream);
    mega_k<<<GRID, 256, 0, stream>>>(x, gamma, w1, b1, w2, b2, out, e, gate, cnt);
}

// Round 12
// 88.487 us; speedup vs baseline: 8.0289x; 2.7132x over previous
//
#include <hip/hip_runtime.h>
#include <math.h>

#define B 8
#define C 512
#define L 8192
#define N 512      // L/CS chunk steps
#define C8 64      // C/8 bottleneck dim
#define CTILE 8    // channels per pool_ema block
#define NT2 4      // chunk rows per se_apply block
#define GSTRIDE 516  // gate LDS row stride (conflict-free apply reads)

// ---------------------------------------------------------------------------
// Kernel 1: fused pooling + full causal EMA.  x [B,C,L] -> e [B,N,C]
// Block = (b, 8-channel tile); owns the whole N timeline for its channels.
// (verified structure from R7; also folds in the tiny weight re-pack)
// ---------------------------------------------------------------------------
__global__ __launch_bounds__(256) void pool_ema_k(
    const float* __restrict__ x, const float* __restrict__ gamma,
    float* __restrict__ e,
    const float* __restrict__ w1, const float* __restrict__ w2,
    float* __restrict__ w1t4, float* __restrict__ w2t4) {
    // per-channel stride 545 dwords: addr = cl*545 + s*17 + i  (s=seg, i=step)
    __shared__ float cm[CTILE * 545];
    __shared__ float carry_s[CTILE][32];
    __shared__ float pre_s[CTILE][32];
    const int t = threadIdx.x;
    const int bid = blockIdx.x;          // B * 64 = 512
    const int ct = bid & 63;
    const int b = bid >> 6;

    // weight repack (first 128 blocks' threads)
    const int gid = bid * 256 + t;
    if (gid < C8 * C) {
        const int o = gid >> 9, k = gid & (C - 1);
        w1t4[((k >> 2) * C8 + o) * 4 + (k & 3)] = w1[gid];
        const int c2 = gid >> 6, k2 = gid & (C8 - 1);
        w2t4[((k2 >> 2) * C + c2) * 4 + (k2 & 3)] = w2[gid];
    }

    const int w = t >> 6, lane = t & 63;
    // ---- Phase A: chunk means (coalesced float4 reads, 8-deep) ----
#pragma unroll
    for (int cr = 0; cr < 2; ++cr) {
        const int cl = w + 4 * cr;
        const size_t row4 = (size_t)(b * C + ct * CTILE + cl) * (L / 4);
#pragma unroll
        for (int rr = 0; rr < 4; ++rr) {
            float4 f[8];
#pragma unroll
            for (int u = 0; u < 8; ++u)
                f[u] = reinterpret_cast<const float4*>(x)[row4 + rr * 512 + u * 64 + lane];
#pragma unroll
            for (int u = 0; u < 8; ++u) {
                float s = f[u].x + f[u].y + f[u].z + f[u].w;
                s += __shfl_down(s, 1, 4);
                s += __shfl_down(s, 2, 4);
                if ((lane & 3) == 0) {
                    const int chunk = rr * 128 + u * 16 + (lane >> 2);
                    cm[cl * 545 + (chunk >> 4) * 17 + (chunk & 15)] = s * (1.0f / 16.0f);
                }
            }
        }
    }
    __syncthreads();

    // ---- Phase B: EMA segmented scan (32 seg x 16 steps) ----
    const int cl = t >> 5, s = t & 31;
    const float g = gamma[ct * CTILE + cl];
    const float omg = 1.0f - g;
    {
        float y = 0.0f;
#pragma unroll
        for (int i = 0; i < 16; ++i)
            y = fmaf(g, y, omg * cm[cl * 545 + s * 17 + i]);
        carry_s[cl][s] = y;
    }
    __syncthreads();
    if (t < CTILE) {
        const float gg = gamma[ct * CTILE + t];
        float g16 = gg * gg; g16 *= g16; g16 *= g16; g16 *= g16;   // g^16
        float E = 0.0f;
#pragma unroll
        for (int ss = 0; ss < 32; ++ss) {
            pre_s[t][ss] = E;
            E = fmaf(g16, E, carry_s[t][ss]);
        }
    }
    __syncthreads();
    {
        float y = pre_s[cl][s];
#pragma unroll
        for (int i = 0; i < 16; ++i) {
            y = fmaf(g, y, omg * cm[cl * 545 + s * 17 + i]);
            cm[cl * 545 + s * 17 + i] = y;
        }
    }
    __syncthreads();

    // ---- write e [B,N,C] ----
    float* ebase = e + (size_t)b * N * C + ct * CTILE;
#pragma unroll
    for (int rr = 0; rr < 16; ++rr) {
        const int idx = rr * 256 + t;
        const int n = idx >> 3, c2 = idx & 7;
        ebase[(size_t)n * C + c2] = cm[c2 * 545 + (n >> 4) * 17 + (n & 15)];
    }
}

// ---------------------------------------------------------------------------
// Kernel 2: fused SE + apply.  Block = (b, 4 chunk-rows n0..n0+3).
// Stage e[4][512] -> GEMM1 -> GEMM2 -> gate in LDS (never global) ->
// apply to x[b, :, n0*16 .. n0*16+64) -> out.  x read hits L3 (K1 just read
// it; only ~8 MB of e touched in between).  1024 blocks, 4/CU.
// ---------------------------------------------------------------------------
__global__ __launch_bounds__(256) void se_apply_k(
    const float* __restrict__ e, const float* __restrict__ w1t4,
    const float* __restrict__ b1, const float* __restrict__ w2t4,
    const float* __restrict__ b2, const float* __restrict__ x,
    float* __restrict__ out) {
    __shared__ float es[NT2 * C];          // 8 KB
    __shared__ float hs[NT2 * C8];         // 1 KB
    __shared__ float gs[NT2 * GSTRIDE];    // 8.25 KB
    const int t = threadIdx.x;
    const int bid = blockIdx.x;            // B * 128 = 1024
    const int b = bid >> 7;
    const int nt = bid & 127;
    const int n0 = nt * NT2;

    // stage e rows n0..n0+3 (coalesced)
    {
        const float4* esrc = reinterpret_cast<const float4*>(e + ((size_t)b * N + n0) * C);
        float4* esw = reinterpret_cast<float4*>(es);
        esw[t] = esrc[t];
        esw[256 + t] = esrc[256 + t];
    }
    __syncthreads();

    // GEMM1: h[4][64] = relu(e x w1^T + b1).  thread = (o = t&63, j = t>>6)
    {
        const int o = t & 63, j = t >> 6;
        float acc = 0.f;
        const float4* w1v = reinterpret_cast<const float4*>(w1t4);
        const float4* es4 = reinterpret_cast<const float4*>(es);
#pragma unroll 8
        for (int k4 = 0; k4 < 128; ++k4) {
            const float4 wv = w1v[k4 * C8 + o];      // lanes: consecutive o -> coalesced
            const float4 ev = es4[j * 128 + k4];     // wave-uniform -> broadcast
            acc = fmaf(wv.x, ev.x, acc); acc = fmaf(wv.y, ev.y, acc);
            acc = fmaf(wv.z, ev.z, acc); acc = fmaf(wv.w, ev.w, acc);
        }
        hs[j * C8 + o] = fmaxf(acc + b1[o], 0.f);
    }
    __syncthreads();

    // GEMM2 + sigmoid -> gs[4][512] (LDS only). thread owns c = t, t+256.
    {
        float acc0[NT2], acc1[NT2];
        const float bb0 = b2[t], bb1 = b2[t + 256];
#pragma unroll
        for (int j = 0; j < NT2; ++j) { acc0[j] = bb0; acc1[j] = bb1; }
        const float4* w2v = reinterpret_cast<const float4*>(w2t4);
        const float4* hs4 = reinterpret_cast<const float4*>(hs);
#pragma unroll
        for (int k4 = 0; k4 < 16; ++k4) {
            const float4 wa = w2v[k4 * C + t];
            const float4 wb = w2v[k4 * C + t + 256];
#pragma unroll
            for (int j = 0; j < NT2; ++j) {
                const float4 hv = hs4[j * 16 + k4];
                acc0[j] = fmaf(wa.x, hv.x, acc0[j]); acc0[j] = fmaf(wa.y, hv.y, acc0[j]);
                acc0[j] = fmaf(wa.z, hv.z, acc0[j]); acc0[j] = fmaf(wa.w, hv.w, acc0[j]);
                acc1[j] = fmaf(wb.x, hv.x, acc1[j]); acc1[j] = fmaf(wb.y, hv.y, acc1[j]);
                acc1[j] = fmaf(wb.z, hv.z, acc1[j]); acc1[j] = fmaf(wb.w, hv.w, acc1[j]);
            }
        }
#pragma unroll
        for (int j = 0; j < NT2; ++j) {
            gs[j * GSTRIDE + t]       = 1.0f / (1.0f + __expf(-acc0[j]));
            gs[j * GSTRIDE + t + 256] = 1.0f / (1.0f + __expf(-acc1[j]));
        }
    }
    __syncthreads();

    // apply: all 512 c-rows, l-range [nt*64, nt*64+64).
    // 16-lane segment per c-row (256 B contiguous); gate from LDS
    // (addr = (q>>2)*516 + r -> 16 distinct banks per wave, conflict-free).
    {
        const size_t base4 = (size_t)b * C * (L / 4) + nt * 16;
        const float4* x4 = reinterpret_cast<const float4*>(x);
        float4* o4 = reinterpret_cast<float4*>(out);
#pragma unroll 4
        for (int i = 0; i < 32; ++i) {
            const int p = i * 256 + t;
            const int r = p >> 4;          // c row 0..511
            const int q = p & 15;          // float4 within the 64-float segment
            const float g = gs[(q >> 2) * GSTRIDE + r];
            const size_t idx = base4 + (size_t)r * (L / 4) + q;
            float4 v = x4[idx];
            v.x *= g; v.y *= g; v.z *= g; v.w *= g;
            o4[idx] = v;
        }
    }
}

// ---------------------------------------------------------------------------
extern "C" void kernel_launch(void* const* d_in, const int* in_sizes, int n_in,
                              void* d_out, int out_size, void* d_ws, size_t ws_size,
                              hipStream_t stream) {
    const float* x     = (const float*)d_in[0];
    const float* gamma = (const float*)d_in[1];
    const float* w1    = (const float*)d_in[2];
    const float* b1    = (const float*)d_in[3];
    const float* w2    = (const float*)d_in[4];
    const float* b2    = (const float*)d_in[5];
    float* out = (float*)d_out;

    char* ws = (char*)d_ws;
    size_t off = 0;
    float* e    = (float*)(ws + off); off += (size_t)B * N * C * 4;   // 8 MB
    float* w1t4 = (float*)(ws + off); off += (size_t)C8 * C * 4;      // 128 KB
    float* w2t4 = (float*)(ws + off); off += (size_t)C8 * C * 4;      // 128 KB

    // K1: fused pooling + full EMA -> e [B,N,C]  (+ weight repack)
    pool_ema_k<<<B * 64, 256, 0, stream>>>(x, gamma, e, w1, w2, w1t4, w2t4);
    // K2: fused SE (gate in LDS) + apply
    se_apply_k<<<B * 128, 256, 0, stream>>>(e, w1t4, b1, w2t4, b2, x, out);
}